// Round 3
// baseline (231.455 us; speedup 1.0000x reference)
//
#include <hip/hip_runtime.h>
#include <hip/hip_bf16.h>
#include <math.h>

// Problem constants
#define NTOK   1024      // 2*512 tokens
#define DIMX   1024
#define INTERX 512
#define NEXP   16
#define RSCALE 2.5f

typedef _Float16 f16x8 __attribute__((ext_vector_type(8)));
typedef float    f32x4 __attribute__((ext_vector_type(4)));

// ws layout (bytes), total ~26.3 MB (same as round 2 — known good)
#define WS_COUNTS   0                              // int[16]
#define WS_OFFSETS  128                            // int[17]
#define WS_TOKIDX   256                            // int[16*1024]
#define WS_SLOTS    (WS_TOKIDX + NEXP*NTOK*4)      // int[1024*4]   (e<<10 | pos)
#define WS_WQ       (WS_SLOTS + NTOK*4*4)          // float[1024*4] (route weights)
#define WS_H        (WS_WQ + NTOK*4*4)             // _Float16[5120*512]
#define WS_YC       (WS_H + 5120*512*2)            // float[5120*1024]

__device__ __forceinline__ void ld4(float4 (&r)[4], const float* p) {
    r[0] = *(const float4*)(p);
    r[1] = *(const float4*)(p + 4);
    r[2] = *(const float4*)(p + 8);
    r[3] = *(const float4*)(p + 12);
}
__device__ __forceinline__ void cvtw(_Float16* d, const float4 (&r)[4]) {
    f16x8 v0 = {(_Float16)r[0].x, (_Float16)r[0].y, (_Float16)r[0].z, (_Float16)r[0].w,
                (_Float16)r[1].x, (_Float16)r[1].y, (_Float16)r[1].z, (_Float16)r[1].w};
    f16x8 v1 = {(_Float16)r[2].x, (_Float16)r[2].y, (_Float16)r[2].z, (_Float16)r[2].w,
                (_Float16)r[3].x, (_Float16)r[3].y, (_Float16)r[3].z, (_Float16)r[3].w};
    *(f16x8*)(d)     = v0;
    *(f16x8*)(d + 8) = v1;
}

// ---------------------------------------------------------------------------
// Gating: scores = sigmoid(x @ gate_w.T); top-4 on (score + bias); weights
// from raw scores, normalized, * 2.5. One wave per token.
// ---------------------------------------------------------------------------
__global__ void gate_topk(const float* __restrict__ x,
                          const float* __restrict__ gw,
                          const float* __restrict__ gb,
                          int* __restrict__ counts,
                          int* __restrict__ tok_idx,
                          int* __restrict__ slots,
                          float* __restrict__ wq)
{
    const int t = blockIdx.x;
    const int lane = threadIdx.x;   // 0..63
    float xv[16];
#pragma unroll
    for (int j = 0; j < 16; ++j) xv[j] = x[t * DIMX + j * 64 + lane];

    float sc[NEXP];
#pragma unroll 1
    for (int e = 0; e < NEXP; ++e) {
        const float* w = gw + e * DIMX;
        float acc = 0.f;
#pragma unroll
        for (int j = 0; j < 16; ++j) acc = fmaf(xv[j], w[j * 64 + lane], acc);
#pragma unroll
        for (int off = 32; off > 0; off >>= 1) acc += __shfl_xor(acc, off);
        sc[e] = acc;
    }

    if (lane == 0) {
        float s[NEXP], b[NEXP];
#pragma unroll
        for (int e = 0; e < NEXP; ++e) {
            float v = 1.f / (1.f + __expf(-sc[e]));
            s[e] = v;
            b[e] = v + gb[e];
        }
        int   idx[4];
        float wsel[4];
        unsigned used = 0;
#pragma unroll
        for (int k = 0; k < 4; ++k) {
            int best = 0; float bv = -1e30f;
#pragma unroll
            for (int e = 0; e < NEXP; ++e) {
                if (!((used >> e) & 1u) && b[e] > bv) { bv = b[e]; best = e; }
            }
            used |= 1u << best;
            idx[k] = best; wsel[k] = s[best];
        }
        float sum = wsel[0] + wsel[1] + wsel[2] + wsel[3];
        float scale = RSCALE / sum;
#pragma unroll
        for (int k = 0; k < 4; ++k) {
            int e = idx[k];
            int pos = atomicAdd(&counts[e], 1);
            tok_idx[e * NTOK + pos] = t;
            slots[t * 4 + k] = (e << 10) | pos;
            wq[t * 4 + k] = wsel[k] * scale;
        }
    }
}

__global__ void prefix16(const int* __restrict__ counts, int* __restrict__ offsets)
{
    if (threadIdx.x == 0 && blockIdx.x == 0) {
        int off = 0;
        for (int e = 0; e < NEXP; ++e) { offsets[e] = off; off += counts[e]; }
        offsets[NEXP] = off;   // == 4096; shared-expert rows follow
    }
}

// ---------------------------------------------------------------------------
// FFN1 (MFMA): h[row, g0..g0+63] = silu(gate)*up of gathered x @ w13_e^T.
// Block 256 = 4 waves (2M x 2N), tile 128 tokens x 128 pre-act rows
// (64 gate + 64 up interleaved so per wave frag f pairs with f+2).
// K-step 32, 2-deep register pipeline, fp32->fp16 cvt during LDS write.
// ---------------------------------------------------------------------------
__global__ __launch_bounds__(256) void ffn1(
    const float* __restrict__ x,
    const float* __restrict__ w13,
    const float* __restrict__ w13s,
    const int* __restrict__ counts,
    const int* __restrict__ offsets,
    const int* __restrict__ tok_idx,
    _Float16* __restrict__ h)
{
    const int e  = blockIdx.z;                      // 0..16 (16 == shared)
    const int Me = (e == NEXP) ? NTOK : counts[e];
    const int m0 = blockIdx.x * 128;
    if (m0 >= Me) return;
    const int g0 = blockIdx.y * 64;                 // h-column base
    const float* __restrict__ W = (e == NEXP) ? w13s
                                : (w13 + (size_t)e * (2 * INTERX) * DIMX);
    const int rowbase = (e == NEXP) ? offsets[NEXP] : offsets[e];

    const int tid  = threadIdx.x;
    const int lane = tid & 63;
    const int wm   = (tid >> 6) >> 1, wn = (tid >> 6) & 1;
    const int li   = lane & 15, rk = (lane >> 4) * 8;

    // staging: thread covers tile-row srow, k-halves [kh, kh+16)
    const int srow = tid >> 1;
    const int kh   = (tid & 1) * 16;

    int mr = m0 + srow; if (mr >= Me) mr = Me - 1;   // clamp; epilogue guards
    const int tokA = (e == NEXP) ? mr : tok_idx[e * NTOK + mr];
    const float* pA = x + (size_t)tokA * DIMX + kh;

    // Bs row c -> w13 row: wn'=c>>6, f=(c>>4)&3, li'=c&15
    // f in {0,1}: gate row g0+wn'*32+f*16+li'; f in {2,3}: up (+512)
    const int bwn = srow >> 6, bf = (srow >> 4) & 3, bli = srow & 15;
    const int w13row = ((bf & 2) ? INTERX : 0) + g0 + bwn * 32 + (bf & 1) * 16 + bli;
    const float* pB = W + (size_t)w13row * DIMX + kh;

    __shared__ _Float16 As[128][40];   // 80B stride: 2-way bank alias (free)
    __shared__ _Float16 Bs[128][40];
    _Float16* wA = &As[srow][kh];
    _Float16* wB = &Bs[srow][kh];

    f32x4 acc[4][4];
#pragma unroll
    for (int i = 0; i < 4; ++i)
#pragma unroll
        for (int f = 0; f < 4; ++f) acc[i][f] = (f32x4){0.f, 0.f, 0.f, 0.f};

    float4 ra[4], rb[4], sa[4], sb[4];
    ld4(ra, pA); ld4(rb, pB);

    auto mmstep = [&]() {
        f16x8 afr[4], bfr[4];
#pragma unroll
        for (int i = 0; i < 4; ++i) afr[i] = *(const f16x8*)&As[wm * 64 + i * 16 + li][rk];
#pragma unroll
        for (int f = 0; f < 4; ++f) bfr[f] = *(const f16x8*)&Bs[wn * 64 + f * 16 + li][rk];
#pragma unroll
        for (int i = 0; i < 4; ++i)
#pragma unroll
            for (int f = 0; f < 4; ++f)
                acc[i][f] = __builtin_amdgcn_mfma_f32_16x16x32_f16(
                    afr[i], bfr[f], acc[i][f], 0, 0, 0);
    };

#pragma unroll 1
    for (int k0 = 0; k0 < DIMX; k0 += 64) {
        __syncthreads();
        ld4(sa, pA + k0 + 32); ld4(sb, pB + k0 + 32);   // prefetch next K-step
        cvtw(wA, ra); cvtw(wB, rb);
        __syncthreads();
        mmstep();
        __syncthreads();
        if (k0 + 64 < DIMX) { ld4(ra, pA + k0 + 64); ld4(rb, pB + k0 + 64); }
        cvtw(wA, sa); cvtw(wB, sb);
        __syncthreads();
        mmstep();
    }

    // epilogue: frag f (gate) pairs with f+2 (up), same lane -> same h-col
#pragma unroll
    for (int i = 0; i < 4; ++i) {
#pragma unroll
        for (int r = 0; r < 4; ++r) {
            const int m = m0 + wm * 64 + i * 16 + (lane >> 4) * 4 + r;
            if (m >= Me) continue;
            _Float16* hp = h + (size_t)(rowbase + m) * INTERX + g0 + wn * 32 + li;
#pragma unroll
            for (int f = 0; f < 2; ++f) {
                const float g = acc[i][f][r];
                const float u = acc[i][f + 2][r];
                hp[f * 16] = (_Float16)(g * u / (1.f + __expf(-g)));
            }
        }
    }
}

// ---------------------------------------------------------------------------
// FFN2 (MFMA): yc[row, n0..n0+127] = h_row @ w2_e^T (route weights later).
// Same pipeline; A is already fp16 (no cvt), B converted during staging.
// ---------------------------------------------------------------------------
__global__ __launch_bounds__(256) void ffn2(
    const float* __restrict__ w2,
    const float* __restrict__ w2s,
    const int* __restrict__ counts,
    const int* __restrict__ offsets,
    const _Float16* __restrict__ h,
    float* __restrict__ yc)
{
    const int e  = blockIdx.z;
    const int Me = (e == NEXP) ? NTOK : counts[e];
    const int m0 = blockIdx.x * 128;
    if (m0 >= Me) return;
    const int n0 = blockIdx.y * 128;
    const float* __restrict__ W = (e == NEXP) ? w2s : (w2 + (size_t)e * DIMX * INTERX);
    const int rowbase = (e == NEXP) ? offsets[NEXP] : offsets[e];

    const int tid  = threadIdx.x;
    const int lane = tid & 63;
    const int wm   = (tid >> 6) >> 1, wn = (tid >> 6) & 1;
    const int li   = lane & 15, rk = (lane >> 4) * 8;

    const int srow = tid >> 1;
    const int kh   = (tid & 1) * 16;

    // A rows stay within h's 5120 rows (proof: rowbase+m0+127 <= 5119)
    const _Float16* pA = h + (size_t)(rowbase + m0 + srow) * INTERX + kh;
    const float*    pB = W + (size_t)(n0 + srow) * INTERX + kh;

    __shared__ _Float16 As[128][40];
    __shared__ _Float16 Bs[128][40];
    _Float16* wA = &As[srow][kh];
    _Float16* wB = &Bs[srow][kh];

    f32x4 acc[4][4];
#pragma unroll
    for (int i = 0; i < 4; ++i)
#pragma unroll
        for (int f = 0; f < 4; ++f) acc[i][f] = (f32x4){0.f, 0.f, 0.f, 0.f};

    f16x8  ra0, ra1, sa0, sa1;
    float4 rb[4], sb[4];
    ra0 = *(const f16x8*)(pA); ra1 = *(const f16x8*)(pA + 8);
    ld4(rb, pB);

    auto mmstep = [&]() {
        f16x8 afr[4], bfr[4];
#pragma unroll
        for (int i = 0; i < 4; ++i) afr[i] = *(const f16x8*)&As[wm * 64 + i * 16 + li][rk];
#pragma unroll
        for (int f = 0; f < 4; ++f) bfr[f] = *(const f16x8*)&Bs[wn * 64 + f * 16 + li][rk];
#pragma unroll
        for (int i = 0; i < 4; ++i)
#pragma unroll
            for (int f = 0; f < 4; ++f)
                acc[i][f] = __builtin_amdgcn_mfma_f32_16x16x32_f16(
                    afr[i], bfr[f], acc[i][f], 0, 0, 0);
    };

#pragma unroll 1
    for (int k0 = 0; k0 < INTERX; k0 += 64) {
        __syncthreads();
        sa0 = *(const f16x8*)(pA + k0 + 32); sa1 = *(const f16x8*)(pA + k0 + 40);
        ld4(sb, pB + k0 + 32);
        *(f16x8*)(wA) = ra0; *(f16x8*)(wA + 8) = ra1;
        cvtw(wB, rb);
        __syncthreads();
        mmstep();
        __syncthreads();
        if (k0 + 64 < INTERX) {
            ra0 = *(const f16x8*)(pA + k0 + 64); ra1 = *(const f16x8*)(pA + k0 + 72);
            ld4(rb, pB + k0 + 64);
        }
        *(f16x8*)(wA) = sa0; *(f16x8*)(wA + 8) = sa1;
        cvtw(wB, sb);
        __syncthreads();
        mmstep();
    }

#pragma unroll
    for (int i = 0; i < 4; ++i) {
#pragma unroll
        for (int r = 0; r < 4; ++r) {
            const int m = m0 + wm * 64 + i * 16 + (lane >> 4) * 4 + r;
            if (m >= Me) continue;
            float* yp = yc + (size_t)(rowbase + m) * DIMX + n0 + wn * 64 + li;
#pragma unroll
            for (int f = 0; f < 4; ++f)
                yp[f * 16] = acc[i][f][r];
        }
    }
}

// ---------------------------------------------------------------------------
// Combine: out[t,:] = yc[shared_row(t),:] + sum_k wq[t,k] * yc[row(t,k),:]
// ---------------------------------------------------------------------------
__global__ __launch_bounds__(256) void combine(
    const int* __restrict__ offsets,
    const int* __restrict__ slots,
    const float* __restrict__ wq,
    const float* __restrict__ yc,
    float* __restrict__ out)
{
    const int t = blockIdx.x;
    const int tid = threadIdx.x;                 // 256 threads x float4 = 1024 cols
    const float4* ycv = (const float4*)yc;
    float4 a = ycv[(size_t)(offsets[NEXP] + t) * 256 + tid];
#pragma unroll
    for (int k = 0; k < 4; ++k) {
        const int s   = slots[t * 4 + k];
        const int e   = s >> 10, pos = s & 1023;
        const float w = wq[t * 4 + k];
        const float4 v = ycv[(size_t)(offsets[e] + pos) * 256 + tid];
        a.x = fmaf(w, v.x, a.x); a.y = fmaf(w, v.y, a.y);
        a.z = fmaf(w, v.z, a.z); a.w = fmaf(w, v.w, a.w);
    }
    ((float4*)out)[(size_t)t * 256 + tid] = a;
}

// ---------------------------------------------------------------------------
extern "C" void kernel_launch(void* const* d_in, const int* in_sizes, int n_in,
                              void* d_out, int out_size, void* d_ws, size_t ws_size,
                              hipStream_t stream)
{
    const float* x    = (const float*)d_in[0];
    // d_in[1] = input_ids (unused)
    const float* gw   = (const float*)d_in[2];
    const float* gb   = (const float*)d_in[3];
    const float* w13  = (const float*)d_in[4];
    const float* w2   = (const float*)d_in[5];
    const float* w13s = (const float*)d_in[6];
    const float* w2s  = (const float*)d_in[7];
    float* out = (float*)d_out;

    char* ws = (char*)d_ws;
    int*       counts  = (int*)(ws + WS_COUNTS);
    int*       offsets = (int*)(ws + WS_OFFSETS);
    int*       tok_idx = (int*)(ws + WS_TOKIDX);
    int*       slots   = (int*)(ws + WS_SLOTS);
    float*     wq      = (float*)(ws + WS_WQ);
    _Float16*  h       = (_Float16*)(ws + WS_H);
    float*     yc      = (float*)(ws + WS_YC);

    hipMemsetAsync(counts, 0, NEXP * sizeof(int), stream);
    gate_topk<<<NTOK, 64, 0, stream>>>(x, gw, gb, counts, tok_idx, slots, wq);
    prefix16<<<1, 64, 0, stream>>>(counts, offsets);

    {   // FFN1: 16 routed experts + shared (z == 16)
        dim3 g(8, 8, 17);
        ffn1<<<g, 256, 0, stream>>>(x, w13, w13s, counts, offsets, tok_idx, h);
    }
    {   // FFN2: all experts write compact yc (no atomics)
        dim3 g(8, 8, 17);
        ffn2<<<g, 256, 0, stream>>>(w2, w2s, counts, offsets, h, yc);
    }
    combine<<<NTOK, 256, 0, stream>>>(offsets, slots, wq, yc, out);
}

// Round 4
// 193.094 us; speedup vs baseline: 1.1987x; 1.1987x over previous
//
#include <hip/hip_runtime.h>
#include <hip/hip_bf16.h>
#include <math.h>

// Problem constants
#define NTOK   1024      // 2*512 tokens
#define DIMX   1024
#define INTERX 512
#define NEXP   16
#define RSCALE 2.5f

typedef _Float16 f16x8 __attribute__((ext_vector_type(8)));
typedef float    f32x4 __attribute__((ext_vector_type(4)));

// fp16 conversion region segment sizes (elements)
#define N_W13  (NEXP * 2 * INTERX * DIMX)   // 16,777,216
#define N_W2   (NEXP * DIMX * INTERX)       //  8,388,608
#define N_W13S (2 * INTERX * DIMX)          //  1,048,576
#define N_W2S  (DIMX * INTERX)              //    524,288
#define N_X    (NTOK * DIMX)                //  1,048,576
#define N_CVT  ((size_t)N_W13 + N_W2 + N_W13S + N_W2S + N_X)   // 27,787,264

// ws layout (bytes)
#define WS_COUNTS  0                                   // int[16]
#define WS_OFFSETS 128                                 // int[17]
#define WS_TOKIDX  256                                 // int[16*1024]
#define WS_SLOTS   (WS_TOKIDX + NEXP * NTOK * 4)       // int[1024*4]
#define WS_WQ      (WS_SLOTS + NTOK * 16)              // float[1024*4]
#define WS_H       (WS_WQ + NTOK * 16)                 // _Float16[5120*512]
#define WS_YC      (WS_H + (size_t)5120 * 512 * 2)     // float[5120*1024]
#define WS_F16     (WS_YC + (size_t)5120 * 1024 * 4)   // _Float16[N_CVT]
#define WS_NEED    (WS_F16 + N_CVT * 2)                // ~78.1 MiB

__device__ __forceinline__ f16x8 ldcvt(const float* __restrict__ p) {
    const float4 a = *(const float4*)p;
    const float4 b = *(const float4*)(p + 4);
    return (f16x8){(_Float16)a.x, (_Float16)a.y, (_Float16)a.z, (_Float16)a.w,
                   (_Float16)b.x, (_Float16)b.y, (_Float16)b.z, (_Float16)b.w};
}

// ---------------------------------------------------------------------------
// Streaming fp32 -> fp16 of [w13 | w2 | w13s | w2s | x] into one region.
// 3392 blocks x 256 threads x 4 grid-stride iters covers 27,787,264/8 exactly.
// ---------------------------------------------------------------------------
__global__ __launch_bounds__(256) void cvt_all(
    const float* __restrict__ w13, const float* __restrict__ w2,
    const float* __restrict__ w13s, const float* __restrict__ w2s,
    const float* __restrict__ x, _Float16* __restrict__ dh)
{
    const size_t stride = (size_t)gridDim.x * blockDim.x;
    for (size_t i8 = (size_t)blockIdx.x * blockDim.x + threadIdx.x;
         i8 < N_CVT / 8; i8 += stride) {
        size_t off = i8 * 8;
        const float* s;
        if (off < N_W13)                       s = w13 + off;
        else if ((off -= N_W13) < N_W2)        s = w2 + off;
        else if ((off -= N_W2) < N_W13S)       s = w13s + off;
        else if ((off -= N_W13S) < N_W2S)      s = w2s + off;
        else                                   s = x + (off - N_W2S);
        *(f16x8*)(dh + i8 * 8) = ldcvt(s);
    }
}

// ---------------------------------------------------------------------------
// Gating: scores = sigmoid(x @ gate_w.T); top-4 on (score + bias); weights
// from raw scores, normalized, * 2.5. One wave per token.
// ---------------------------------------------------------------------------
__global__ void gate_topk(const float* __restrict__ x,
                          const float* __restrict__ gw,
                          const float* __restrict__ gb,
                          int* __restrict__ counts,
                          int* __restrict__ tok_idx,
                          int* __restrict__ slots,
                          float* __restrict__ wq)
{
    const int t = blockIdx.x;
    const int lane = threadIdx.x;   // 0..63
    float xv[16];
#pragma unroll
    for (int j = 0; j < 16; ++j) xv[j] = x[t * DIMX + j * 64 + lane];

    float sc[NEXP];
#pragma unroll 1
    for (int e = 0; e < NEXP; ++e) {
        const float* w = gw + e * DIMX;
        float acc = 0.f;
#pragma unroll
        for (int j = 0; j < 16; ++j) acc = fmaf(xv[j], w[j * 64 + lane], acc);
#pragma unroll
        for (int off = 32; off > 0; off >>= 1) acc += __shfl_xor(acc, off);
        sc[e] = acc;
    }

    if (lane == 0) {
        float s[NEXP], b[NEXP];
#pragma unroll
        for (int e = 0; e < NEXP; ++e) {
            float v = 1.f / (1.f + __expf(-sc[e]));
            s[e] = v;
            b[e] = v + gb[e];
        }
        int   idx[4];
        float wsel[4];
        unsigned used = 0;
#pragma unroll
        for (int k = 0; k < 4; ++k) {
            int best = 0; float bv = -1e30f;
#pragma unroll
            for (int e = 0; e < NEXP; ++e) {
                if (!((used >> e) & 1u) && b[e] > bv) { bv = b[e]; best = e; }
            }
            used |= 1u << best;
            idx[k] = best; wsel[k] = s[best];
        }
        float sum = wsel[0] + wsel[1] + wsel[2] + wsel[3];
        float scale = RSCALE / sum;
#pragma unroll
        for (int k = 0; k < 4; ++k) {
            int e = idx[k];
            int pos = atomicAdd(&counts[e], 1);
            tok_idx[e * NTOK + pos] = t;
            slots[t * 4 + k] = (e << 10) | pos;
            wq[t * 4 + k] = wsel[k] * scale;
        }
    }
}

__global__ void prefix16(const int* __restrict__ counts, int* __restrict__ offsets)
{
    if (threadIdx.x == 0 && blockIdx.x == 0) {
        int off = 0;
        for (int e = 0; e < NEXP; ++e) { offsets[e] = off; off += counts[e]; }
        offsets[NEXP] = off;   // == 4096; shared-expert rows follow
    }
}

struct Stage { f16x8 a0, a1, b0, b1, b2, b3; };

// ---------------------------------------------------------------------------
// FFN1 (MFMA): h[row, g0..g0+63] = silu(gate)*up of gathered x @ w13_e^T.
// Block 256 = 4 waves (2M x 2N), tile 64 tokens x 128 pre-act rows.
// K-step 64, reg ping-pong prefetch, fp16 inputs (F16W) or inline cvt.
// ---------------------------------------------------------------------------
template <bool F16W>
__global__ __launch_bounds__(256) void ffn1(
    const float* __restrict__ xf, const _Float16* __restrict__ xh,
    const float* __restrict__ w13f, const float* __restrict__ w13sf,
    const _Float16* __restrict__ w13h, const _Float16* __restrict__ w13sh,
    const int* __restrict__ counts, const int* __restrict__ offsets,
    const int* __restrict__ tok_idx, _Float16* __restrict__ h)
{
    const int e  = blockIdx.z;                      // 0..16 (16 == shared)
    const int Me = (e == NEXP) ? NTOK : counts[e];
    const int m0 = blockIdx.x * 64;
    if (m0 >= Me) return;
    const int g0 = blockIdx.y * 64;                 // h-column base
    const int rowbase = (e == NEXP) ? offsets[NEXP] : offsets[e];

    const int tid = threadIdx.x, lane = tid & 63;
    const int wm = tid >> 7, wn = (tid >> 6) & 1;
    const int li = lane & 15, rk = (lane >> 4) * 8;

    const int sr = tid >> 3;          // staging row 0..31
    const int sc = (tid & 7) * 8;     // staging k-offset (halves)

    int ma0 = m0 + sr;      if (ma0 >= Me) ma0 = Me - 1;
    int ma1 = m0 + sr + 32; if (ma1 >= Me) ma1 = Me - 1;
    const int tok0 = (e == NEXP) ? ma0 : tok_idx[e * NTOK + ma0];
    const int tok1 = (e == NEXP) ? ma1 : tok_idx[e * NTOK + ma1];

    // Bs row c -> w13 row (frag f<2: gate, f>=2: up of same h-col)
    size_t boff[4];
#pragma unroll
    for (int j = 0; j < 4; ++j) {
        const int c = sr + 32 * j;
        const int bwn = c >> 6, bf = (c >> 4) & 3, bli = c & 15;
        const int row = ((bf & 2) ? INTERX : 0) + g0 + bwn * 32 + (bf & 1) * 16 + bli;
        boff[j] = (size_t)row * DIMX + sc;
    }
    const _Float16* Wh = (e == NEXP) ? w13sh : (w13h + (size_t)e * (2 * INTERX) * DIMX);
    const float*    Wf = (e == NEXP) ? w13sf : (w13f + (size_t)e * (2 * INTERX) * DIMX);
    const size_t aoff0 = (size_t)tok0 * DIMX + sc;
    const size_t aoff1 = (size_t)tok1 * DIMX + sc;

    __shared__ _Float16 As[64][72];    // 144B stride: 2-way bank alias (free)
    __shared__ _Float16 Bs[128][72];

    f32x4 acc[2][4];
#pragma unroll
    for (int i = 0; i < 2; ++i)
#pragma unroll
        for (int f = 0; f < 4; ++f) acc[i][f] = (f32x4){0.f, 0.f, 0.f, 0.f};

    auto LD = [&](int k) -> Stage {
        Stage st;
        if constexpr (F16W) {
            st.a0 = *(const f16x8*)(xh + aoff0 + k);
            st.a1 = *(const f16x8*)(xh + aoff1 + k);
            st.b0 = *(const f16x8*)(Wh + boff[0] + k);
            st.b1 = *(const f16x8*)(Wh + boff[1] + k);
            st.b2 = *(const f16x8*)(Wh + boff[2] + k);
            st.b3 = *(const f16x8*)(Wh + boff[3] + k);
        } else {
            st.a0 = ldcvt(xf + aoff0 + k);
            st.a1 = ldcvt(xf + aoff1 + k);
            st.b0 = ldcvt(Wf + boff[0] + k);
            st.b1 = ldcvt(Wf + boff[1] + k);
            st.b2 = ldcvt(Wf + boff[2] + k);
            st.b3 = ldcvt(Wf + boff[3] + k);
        }
        return st;
    };
    auto WR = [&](const Stage& st) {
        *(f16x8*)&As[sr][sc]      = st.a0;
        *(f16x8*)&As[sr + 32][sc] = st.a1;
        *(f16x8*)&Bs[sr][sc]      = st.b0;
        *(f16x8*)&Bs[sr + 32][sc] = st.b1;
        *(f16x8*)&Bs[sr + 64][sc] = st.b2;
        *(f16x8*)&Bs[sr + 96][sc] = st.b3;
    };
    auto MM = [&]() {
#pragma unroll
        for (int kk = 0; kk < 64; kk += 32) {
            f16x8 afr[2], bfr[4];
#pragma unroll
            for (int i = 0; i < 2; ++i)
                afr[i] = *(const f16x8*)&As[wm * 32 + i * 16 + li][kk + rk];
#pragma unroll
            for (int f = 0; f < 4; ++f)
                bfr[f] = *(const f16x8*)&Bs[wn * 64 + f * 16 + li][kk + rk];
#pragma unroll
            for (int i = 0; i < 2; ++i)
#pragma unroll
                for (int f = 0; f < 4; ++f)
                    acc[i][f] = __builtin_amdgcn_mfma_f32_16x16x32_f16(
                        afr[i], bfr[f], acc[i][f], 0, 0, 0);
        }
    };

    Stage r = LD(0), s;
#pragma unroll 1
    for (int k0 = 0; k0 < DIMX; k0 += 128) {
        __syncthreads();
        s = LD(k0 + 64);
        WR(r);
        __syncthreads();
        MM();
        __syncthreads();
        if (k0 + 128 < DIMX) r = LD(k0 + 128);
        WR(s);
        __syncthreads();
        MM();
    }

    // epilogue: frag f (gate) pairs with f+2 (up), same lane -> same h-col
#pragma unroll
    for (int i = 0; i < 2; ++i) {
#pragma unroll
        for (int q = 0; q < 4; ++q) {
            const int m = m0 + wm * 32 + i * 16 + (lane >> 4) * 4 + q;
            if (m >= Me) continue;
            _Float16* hp = h + (size_t)(rowbase + m) * INTERX + g0 + wn * 32 + li;
#pragma unroll
            for (int f = 0; f < 2; ++f) {
                const float g = acc[i][f][q];
                const float u = acc[i][f + 2][q];
                hp[f * 16] = (_Float16)(g * u / (1.f + __expf(-g)));
            }
        }
    }
}

// ---------------------------------------------------------------------------
// FFN2 (MFMA): yc[row, n0..n0+127] = h_row @ w2_e^T (route weights later).
// ---------------------------------------------------------------------------
template <bool F16W>
__global__ __launch_bounds__(256) void ffn2(
    const float* __restrict__ w2f, const float* __restrict__ w2sf,
    const _Float16* __restrict__ w2h, const _Float16* __restrict__ w2sh,
    const int* __restrict__ counts, const int* __restrict__ offsets,
    const _Float16* __restrict__ h, float* __restrict__ yc)
{
    const int e  = blockIdx.z;
    const int Me = (e == NEXP) ? NTOK : counts[e];
    const int m0 = blockIdx.x * 64;
    if (m0 >= Me) return;
    const int n0 = blockIdx.y * 128;
    const int rowbase = (e == NEXP) ? offsets[NEXP] : offsets[e];

    const int tid = threadIdx.x, lane = tid & 63;
    const int wm = tid >> 7, wn = (tid >> 6) & 1;
    const int li = lane & 15, rk = (lane >> 4) * 8;

    const int sr = tid >> 3;
    const int sc = (tid & 7) * 8;

    // A rows rowbase+m0+sr(+32) always within h's 5120 rows
    const _Float16* pA0 = h + (size_t)(rowbase + m0 + sr) * INTERX + sc;
    const _Float16* pA1 = pA0 + (size_t)32 * INTERX;
    const _Float16* Wh = (e == NEXP) ? w2sh : (w2h + (size_t)e * DIMX * INTERX);
    const float*    Wf = (e == NEXP) ? w2sf : (w2f + (size_t)e * DIMX * INTERX);
    size_t boff[4];
#pragma unroll
    for (int j = 0; j < 4; ++j) boff[j] = (size_t)(n0 + sr + 32 * j) * INTERX + sc;

    __shared__ _Float16 As[64][72];
    __shared__ _Float16 Bs[128][72];

    f32x4 acc[2][4];
#pragma unroll
    for (int i = 0; i < 2; ++i)
#pragma unroll
        for (int f = 0; f < 4; ++f) acc[i][f] = (f32x4){0.f, 0.f, 0.f, 0.f};

    auto LD = [&](int k) -> Stage {
        Stage st;
        st.a0 = *(const f16x8*)(pA0 + k);
        st.a1 = *(const f16x8*)(pA1 + k);
        if constexpr (F16W) {
            st.b0 = *(const f16x8*)(Wh + boff[0] + k);
            st.b1 = *(const f16x8*)(Wh + boff[1] + k);
            st.b2 = *(const f16x8*)(Wh + boff[2] + k);
            st.b3 = *(const f16x8*)(Wh + boff[3] + k);
        } else {
            st.b0 = ldcvt(Wf + boff[0] + k);
            st.b1 = ldcvt(Wf + boff[1] + k);
            st.b2 = ldcvt(Wf + boff[2] + k);
            st.b3 = ldcvt(Wf + boff[3] + k);
        }
        return st;
    };
    auto WR = [&](const Stage& st) {
        *(f16x8*)&As[sr][sc]      = st.a0;
        *(f16x8*)&As[sr + 32][sc] = st.a1;
        *(f16x8*)&Bs[sr][sc]      = st.b0;
        *(f16x8*)&Bs[sr + 32][sc] = st.b1;
        *(f16x8*)&Bs[sr + 64][sc] = st.b2;
        *(f16x8*)&Bs[sr + 96][sc] = st.b3;
    };
    auto MM = [&]() {
#pragma unroll
        for (int kk = 0; kk < 64; kk += 32) {
            f16x8 afr[2], bfr[4];
#pragma unroll
            for (int i = 0; i < 2; ++i)
                afr[i] = *(const f16x8*)&As[wm * 32 + i * 16 + li][kk + rk];
#pragma unroll
            for (int f = 0; f < 4; ++f)
                bfr[f] = *(const f16x8*)&Bs[wn * 64 + f * 16 + li][kk + rk];
#pragma unroll
            for (int i = 0; i < 2; ++i)
#pragma unroll
                for (int f = 0; f < 4; ++f)
                    acc[i][f] = __builtin_amdgcn_mfma_f32_16x16x32_f16(
                        afr[i], bfr[f], acc[i][f], 0, 0, 0);
        }
    };

    Stage r = LD(0), s;
#pragma unroll 1
    for (int k0 = 0; k0 < INTERX; k0 += 128) {
        __syncthreads();
        s = LD(k0 + 64);
        WR(r);
        __syncthreads();
        MM();
        __syncthreads();
        if (k0 + 128 < INTERX) r = LD(k0 + 128);
        WR(s);
        __syncthreads();
        MM();
    }

#pragma unroll
    for (int i = 0; i < 2; ++i) {
#pragma unroll
        for (int q = 0; q < 4; ++q) {
            const int m = m0 + wm * 32 + i * 16 + (lane >> 4) * 4 + q;
            if (m >= Me) continue;
            float* yp = yc + (size_t)(rowbase + m) * DIMX + n0 + wn * 64 + li;
#pragma unroll
            for (int f = 0; f < 4; ++f)
                yp[f * 16] = acc[i][f][q];
        }
    }
}

// ---------------------------------------------------------------------------
// Combine: out[t,:] = yc[shared_row(t),:] + sum_k wq[t,k] * yc[row(t,k),:]
// ---------------------------------------------------------------------------
__global__ __launch_bounds__(256) void combine(
    const int* __restrict__ offsets,
    const int* __restrict__ slots,
    const float* __restrict__ wq,
    const float* __restrict__ yc,
    float* __restrict__ out)
{
    const int t = blockIdx.x;
    const int tid = threadIdx.x;                 // 256 threads x float4 = 1024 cols
    const float4* ycv = (const float4*)yc;
    float4 a = ycv[(size_t)(offsets[NEXP] + t) * 256 + tid];
#pragma unroll
    for (int k = 0; k < 4; ++k) {
        const int s   = slots[t * 4 + k];
        const int e   = s >> 10, pos = s & 1023;
        const float w = wq[t * 4 + k];
        const float4 v = ycv[(size_t)(offsets[e] + pos) * 256 + tid];
        a.x = fmaf(w, v.x, a.x); a.y = fmaf(w, v.y, a.y);
        a.z = fmaf(w, v.z, a.z); a.w = fmaf(w, v.w, a.w);
    }
    ((float4*)out)[(size_t)t * 256 + tid] = a;
}

// ---------------------------------------------------------------------------
extern "C" void kernel_launch(void* const* d_in, const int* in_sizes, int n_in,
                              void* d_out, int out_size, void* d_ws, size_t ws_size,
                              hipStream_t stream)
{
    const float* x    = (const float*)d_in[0];
    // d_in[1] = input_ids (unused)
    const float* gw   = (const float*)d_in[2];
    const float* gb   = (const float*)d_in[3];
    const float* w13  = (const float*)d_in[4];
    const float* w2   = (const float*)d_in[5];
    const float* w13s = (const float*)d_in[6];
    const float* w2s  = (const float*)d_in[7];
    float* out = (float*)d_out;

    char* ws = (char*)d_ws;
    int*       counts  = (int*)(ws + WS_COUNTS);
    int*       offsets = (int*)(ws + WS_OFFSETS);
    int*       tok_idx = (int*)(ws + WS_TOKIDX);
    int*       slots   = (int*)(ws + WS_SLOTS);
    float*     wq      = (float*)(ws + WS_WQ);
    _Float16*  h       = (_Float16*)(ws + WS_H);
    float*     yc      = (float*)(ws + WS_YC);
    _Float16*  dh      = (_Float16*)(ws + WS_F16);
    _Float16*  w13h    = dh;
    _Float16*  w2h     = w13h + N_W13;
    _Float16*  w13sh   = w2h + N_W2;
    _Float16*  w2sh    = w13sh + N_W13S;
    _Float16*  xh      = w2sh + N_W2S;

    const bool F16 = (ws_size >= WS_NEED);

    hipMemsetAsync(counts, 0, NEXP * sizeof(int), stream);
    if (F16)
        cvt_all<<<3392, 256, 0, stream>>>(w13, w2, w13s, w2s, x, dh);
    gate_topk<<<NTOK, 64, 0, stream>>>(x, gw, gb, counts, tok_idx, slots, wq);
    prefix16<<<1, 64, 0, stream>>>(counts, offsets);

    dim3 g1(16, 8, 17);   // m-tiles, h-col tiles, experts(+shared)
    dim3 g2(16, 8, 17);   // m-tiles, out-col tiles, experts(+shared)
    if (F16) {
        ffn1<true><<<g1, 256, 0, stream>>>(x, xh, w13, w13s, w13h, w13sh,
                                           counts, offsets, tok_idx, h);
        ffn2<true><<<g2, 256, 0, stream>>>(w2, w2s, w2h, w2sh,
                                           counts, offsets, h, yc);
    } else {
        ffn1<false><<<g1, 256, 0, stream>>>(x, xh, w13, w13s, w13h, w13sh,
                                            counts, offsets, tok_idx, h);
        ffn2<false><<<g2, 256, 0, stream>>>(w2, w2s, w2h, w2sh,
                                            counts, offsets, h, yc);
    }
    combine<<<NTOK, 256, 0, stream>>>(offsets, slots, wq, yc, out);
}

// Round 5
// 173.690 us; speedup vs baseline: 1.3326x; 1.1117x over previous
//
#include <hip/hip_runtime.h>
#include <hip/hip_bf16.h>
#include <math.h>

// Problem constants
#define NTOK   1024      // 2*512 tokens
#define DIMX   1024
#define INTERX 512
#define NEXP   16
#define RSCALE 2.5f

typedef _Float16 f16x8 __attribute__((ext_vector_type(8)));
typedef float    f32x4 __attribute__((ext_vector_type(4)));

// fp16 conversion region segment sizes (elements)
#define N_W13  (NEXP * 2 * INTERX * DIMX)   // 16,777,216
#define N_W2   (NEXP * DIMX * INTERX)       //  8,388,608
#define N_W13S (2 * INTERX * DIMX)          //  1,048,576
#define N_W2S  (DIMX * INTERX)              //    524,288
#define N_X    (NTOK * DIMX)                //  1,048,576
#define N_CVT  ((size_t)N_W13 + N_W2 + N_W13S + N_W2S + N_X)   // 27,787,264

// ws layout (bytes)
#define WS_COUNTS  0                                   // int[16]
#define WS_TOKIDX  256                                 // int[16*1024]
#define WS_SLOTS   (WS_TOKIDX + NEXP * NTOK * 4)       // int[1024*4]
#define WS_WQ      (WS_SLOTS + NTOK * 16)              // float[1024*4]
#define WS_H       (WS_WQ + NTOK * 16)                 // _Float16[5120*512]
#define WS_YC      (WS_H + (size_t)5120 * 512 * 2)     // float[5120*1024]
#define WS_F16     (WS_YC + (size_t)5120 * 1024 * 4)   // _Float16[N_CVT]
#define WS_NEED    (WS_F16 + N_CVT * 2)                // ~78.1 MiB

// XOR-swizzled LDS addressing: row stride 64 halves (128B), k granule 8 halves.
// Write (r, k) and read (r, k) with the same map -> bank-floor b128 access.
#define SWZ(r, k) ((r) * 64 + ((k) ^ (((r) & 7) << 3)))

__device__ __forceinline__ f16x8 ldcvt(const float* __restrict__ p) {
    const float4 a = *(const float4*)p;
    const float4 b = *(const float4*)(p + 4);
    return (f16x8){(_Float16)a.x, (_Float16)a.y, (_Float16)a.z, (_Float16)a.w,
                   (_Float16)b.x, (_Float16)b.y, (_Float16)b.z, (_Float16)b.w};
}

// ---------------------------------------------------------------------------
// Fused: blocks [0,256)  -> gating (4 tokens/block, one wave each)
//        blocks [256,...) -> streaming fp32->fp16 cvt of [w13|w2|w13s|w2s|x]
// ---------------------------------------------------------------------------
#define CVT_BLOCKS 3392
__global__ __launch_bounds__(256) void cvt_gate(
    const float* __restrict__ w13, const float* __restrict__ w2,
    const float* __restrict__ w13s, const float* __restrict__ w2s,
    const float* __restrict__ x, _Float16* __restrict__ dh,
    const float* __restrict__ gw, const float* __restrict__ gb,
    int* __restrict__ counts, int* __restrict__ tok_idx,
    int* __restrict__ slots, float* __restrict__ wq)
{
    if (blockIdx.x < 256) {
        // ---- gating ----
        const int lane = threadIdx.x & 63;
        const int t = blockIdx.x * 4 + (threadIdx.x >> 6);

        float xv[16];
#pragma unroll
        for (int j = 0; j < 16; ++j) xv[j] = x[t * DIMX + j * 64 + lane];

        float acc[NEXP];
#pragma unroll
        for (int e = 0; e < NEXP; ++e) acc[e] = 0.f;
#pragma unroll
        for (int j = 0; j < 16; ++j) {
            float wv[NEXP];
#pragma unroll
            for (int e = 0; e < NEXP; ++e) wv[e] = gw[e * DIMX + j * 64 + lane];
#pragma unroll
            for (int e = 0; e < NEXP; ++e) acc[e] = fmaf(xv[j], wv[e], acc[e]);
        }
#pragma unroll
        for (int e = 0; e < NEXP; ++e) {
#pragma unroll
            for (int off = 32; off > 0; off >>= 1)
                acc[e] += __shfl_xor(acc[e], off);
        }

        if (lane == 0) {
            float s[NEXP], b[NEXP];
#pragma unroll
            for (int e = 0; e < NEXP; ++e) {
                float v = 1.f / (1.f + __expf(-acc[e]));
                s[e] = v;
                b[e] = v + gb[e];
            }
            int idx[4]; float wsel[4];
            unsigned used = 0;
#pragma unroll
            for (int k = 0; k < 4; ++k) {
                int best = 0; float bv = -1e30f;
#pragma unroll
                for (int e = 0; e < NEXP; ++e)
                    if (!((used >> e) & 1u) && b[e] > bv) { bv = b[e]; best = e; }
                used |= 1u << best;
                idx[k] = best; wsel[k] = s[best];
            }
            const float scale = RSCALE / (wsel[0] + wsel[1] + wsel[2] + wsel[3]);
#pragma unroll
            for (int k = 0; k < 4; ++k) {
                const int e = idx[k];
                const int pos = atomicAdd(&counts[e], 1);
                tok_idx[e * NTOK + pos] = t;
                slots[t * 4 + k] = (e << 10) | pos;
                wq[t * 4 + k] = wsel[k] * scale;
            }
        }
        return;
    }
    // ---- cvt ----
    const size_t stride = (size_t)CVT_BLOCKS * blockDim.x;
    for (size_t i8 = (size_t)(blockIdx.x - 256) * blockDim.x + threadIdx.x;
         i8 < N_CVT / 8; i8 += stride) {
        size_t off = i8 * 8;
        const float* s;
        if (off < N_W13)                       s = w13 + off;
        else if ((off -= N_W13) < N_W2)        s = w2 + off;
        else if ((off -= N_W2) < N_W13S)       s = w13s + off;
        else if ((off -= N_W13S) < N_W2S)      s = w2s + off;
        else                                   s = x + (off - N_W2S);
        *(f16x8*)(dh + i8 * 8) = ldcvt(s);
    }
}

struct Stage { f16x8 a0, a1, b0, b1, b2, b3; };

// ---------------------------------------------------------------------------
// FFN1 (MFMA): h[row, g0..g0+63] = silu(gate)*up of gathered x @ w13_e^T.
// Block 256 = 4 waves (2M x 2N), tile 64 tokens x 128 pre-act rows.
// K-step 64, double-buffered LDS (1 barrier/step), loads 2 steps ahead.
// ---------------------------------------------------------------------------
template <bool F16W>
__global__ __launch_bounds__(256) void ffn1(
    const float* __restrict__ xf, const _Float16* __restrict__ xh,
    const float* __restrict__ w13f, const float* __restrict__ w13sf,
    const _Float16* __restrict__ w13h, const _Float16* __restrict__ w13sh,
    const int* __restrict__ counts, const int* __restrict__ tok_idx,
    _Float16* __restrict__ h)
{
    const int e  = blockIdx.z;                      // 0..16 (16 == shared)
    const int Me = (e == NEXP) ? NTOK : counts[e];
    const int m0 = blockIdx.x * 64;
    if (m0 >= Me) return;
    const int g0 = blockIdx.y * 64;                 // h-column base
    int rowbase = 0;
    if (e == NEXP) rowbase = 4096;                  // sum(counts) == 4*NTOK
    else for (int i = 0; i < e; ++i) rowbase += counts[i];

    const int tid = threadIdx.x, lane = tid & 63;
    const int wm = tid >> 7, wn = (tid >> 6) & 1;
    const int li = lane & 15, rk = (lane >> 4) * 8;

    const int sr = tid >> 3;          // staging row 0..31
    const int sc = (tid & 7) * 8;     // staging k-offset (halves)

    int ma0 = m0 + sr;      if (ma0 >= Me) ma0 = Me - 1;
    int ma1 = m0 + sr + 32; if (ma1 >= Me) ma1 = Me - 1;
    const int tok0 = (e == NEXP) ? ma0 : tok_idx[e * NTOK + ma0];
    const int tok1 = (e == NEXP) ? ma1 : tok_idx[e * NTOK + ma1];

    // Bs row c -> w13 row (frag f<2: gate, f>=2: up of same h-col)
    size_t boff[4];
#pragma unroll
    for (int j = 0; j < 4; ++j) {
        const int c = sr + 32 * j;
        const int bwn = c >> 6, bf = (c >> 4) & 3, bli = c & 15;
        const int row = ((bf & 2) ? INTERX : 0) + g0 + bwn * 32 + (bf & 1) * 16 + bli;
        boff[j] = (size_t)row * DIMX + sc;
    }
    const _Float16* Wh = (e == NEXP) ? w13sh : (w13h + (size_t)e * (2 * INTERX) * DIMX);
    const float*    Wf = (e == NEXP) ? w13sf : (w13f + (size_t)e * (2 * INTERX) * DIMX);
    const size_t aoff0 = (size_t)tok0 * DIMX + sc;
    const size_t aoff1 = (size_t)tok1 * DIMX + sc;

    __shared__ _Float16 As[2][64 * 64];   // swizzled, no padding
    __shared__ _Float16 Bs[2][128 * 64];

    f32x4 acc[2][4];
#pragma unroll
    for (int i = 0; i < 2; ++i)
#pragma unroll
        for (int f = 0; f < 4; ++f) acc[i][f] = (f32x4){0.f, 0.f, 0.f, 0.f};

    auto LD = [&](int k) -> Stage {
        Stage st;
        if constexpr (F16W) {
            st.a0 = *(const f16x8*)(xh + aoff0 + k);
            st.a1 = *(const f16x8*)(xh + aoff1 + k);
            st.b0 = *(const f16x8*)(Wh + boff[0] + k);
            st.b1 = *(const f16x8*)(Wh + boff[1] + k);
            st.b2 = *(const f16x8*)(Wh + boff[2] + k);
            st.b3 = *(const f16x8*)(Wh + boff[3] + k);
        } else {
            st.a0 = ldcvt(xf + aoff0 + k);
            st.a1 = ldcvt(xf + aoff1 + k);
            st.b0 = ldcvt(Wf + boff[0] + k);
            st.b1 = ldcvt(Wf + boff[1] + k);
            st.b2 = ldcvt(Wf + boff[2] + k);
            st.b3 = ldcvt(Wf + boff[3] + k);
        }
        return st;
    };
    auto WRb = [&](int b, const Stage& st) {
        *(f16x8*)&As[b][SWZ(sr, sc)]      = st.a0;
        *(f16x8*)&As[b][SWZ(sr + 32, sc)] = st.a1;
        *(f16x8*)&Bs[b][SWZ(sr, sc)]      = st.b0;
        *(f16x8*)&Bs[b][SWZ(sr + 32, sc)] = st.b1;
        *(f16x8*)&Bs[b][SWZ(sr + 64, sc)] = st.b2;
        *(f16x8*)&Bs[b][SWZ(sr + 96, sc)] = st.b3;
    };
    auto MM = [&](int b) {
#pragma unroll
        for (int kk = 0; kk < 64; kk += 32) {
            f16x8 afr[2], bfr[4];
#pragma unroll
            for (int i = 0; i < 2; ++i)
                afr[i] = *(const f16x8*)&As[b][SWZ(wm * 32 + i * 16 + li, kk + rk)];
#pragma unroll
            for (int f = 0; f < 4; ++f)
                bfr[f] = *(const f16x8*)&Bs[b][SWZ(wn * 64 + f * 16 + li, kk + rk)];
#pragma unroll
            for (int i = 0; i < 2; ++i)
#pragma unroll
                for (int f = 0; f < 4; ++f)
                    acc[i][f] = __builtin_amdgcn_mfma_f32_16x16x32_f16(
                        afr[i], bfr[f], acc[i][f], 0, 0, 0);
        }
    };

    Stage r = LD(0);
    WRb(0, r);
    r = LD(64);
    int cur = 0;
#pragma unroll 1
    for (int t = 0; t < DIMX / 64; ++t) {
        __syncthreads();
        Stage nxt = LD(t + 2 < DIMX / 64 ? (t + 2) * 64 : 0);
        MM(cur);
        WRb(cur ^ 1, r);    // last-iter write is to the dead buffer (harmless)
        r = nxt;
        cur ^= 1;
    }

    // epilogue: frag f (gate) pairs with f+2 (up), same lane -> same h-col
#pragma unroll
    for (int i = 0; i < 2; ++i) {
#pragma unroll
        for (int q = 0; q < 4; ++q) {
            const int m = m0 + wm * 32 + i * 16 + (lane >> 4) * 4 + q;
            if (m >= Me) continue;
            _Float16* hp = h + (size_t)(rowbase + m) * INTERX + g0 + wn * 32 + li;
#pragma unroll
            for (int f = 0; f < 2; ++f) {
                const float g = acc[i][f][q];
                const float u = acc[i][f + 2][q];
                hp[f * 16] = (_Float16)(g * u / (1.f + __expf(-g)));
            }
        }
    }
}

// ---------------------------------------------------------------------------
// FFN2 (MFMA): yc[row, n0..n0+127] = h_row @ w2_e^T (route weights later).
// ---------------------------------------------------------------------------
template <bool F16W>
__global__ __launch_bounds__(256) void ffn2(
    const float* __restrict__ w2f, const float* __restrict__ w2sf,
    const _Float16* __restrict__ w2h, const _Float16* __restrict__ w2sh,
    const int* __restrict__ counts, const _Float16* __restrict__ h,
    float* __restrict__ yc)
{
    const int e  = blockIdx.z;
    const int Me = (e == NEXP) ? NTOK : counts[e];
    const int m0 = blockIdx.x * 64;
    if (m0 >= Me) return;
    const int n0 = blockIdx.y * 128;
    int rowbase = 0;
    if (e == NEXP) rowbase = 4096;
    else for (int i = 0; i < e; ++i) rowbase += counts[i];

    const int tid = threadIdx.x, lane = tid & 63;
    const int wm = tid >> 7, wn = (tid >> 6) & 1;
    const int li = lane & 15, rk = (lane >> 4) * 8;

    const int sr = tid >> 3;
    const int sc = (tid & 7) * 8;

    const _Float16* pA0 = h + (size_t)(rowbase + m0 + sr) * INTERX + sc;
    const _Float16* pA1 = pA0 + (size_t)32 * INTERX;
    const _Float16* Wh = (e == NEXP) ? w2sh : (w2h + (size_t)e * DIMX * INTERX);
    const float*    Wf = (e == NEXP) ? w2sf : (w2f + (size_t)e * DIMX * INTERX);
    size_t boff[4];
#pragma unroll
    for (int j = 0; j < 4; ++j) boff[j] = (size_t)(n0 + sr + 32 * j) * INTERX + sc;

    __shared__ _Float16 As[2][64 * 64];
    __shared__ _Float16 Bs[2][128 * 64];

    f32x4 acc[2][4];
#pragma unroll
    for (int i = 0; i < 2; ++i)
#pragma unroll
        for (int f = 0; f < 4; ++f) acc[i][f] = (f32x4){0.f, 0.f, 0.f, 0.f};

    auto LD = [&](int k) -> Stage {
        Stage st;
        st.a0 = *(const f16x8*)(pA0 + k);
        st.a1 = *(const f16x8*)(pA1 + k);
        if constexpr (F16W) {
            st.b0 = *(const f16x8*)(Wh + boff[0] + k);
            st.b1 = *(const f16x8*)(Wh + boff[1] + k);
            st.b2 = *(const f16x8*)(Wh + boff[2] + k);
            st.b3 = *(const f16x8*)(Wh + boff[3] + k);
        } else {
            st.b0 = ldcvt(Wf + boff[0] + k);
            st.b1 = ldcvt(Wf + boff[1] + k);
            st.b2 = ldcvt(Wf + boff[2] + k);
            st.b3 = ldcvt(Wf + boff[3] + k);
        }
        return st;
    };
    auto WRb = [&](int b, const Stage& st) {
        *(f16x8*)&As[b][SWZ(sr, sc)]      = st.a0;
        *(f16x8*)&As[b][SWZ(sr + 32, sc)] = st.a1;
        *(f16x8*)&Bs[b][SWZ(sr, sc)]      = st.b0;
        *(f16x8*)&Bs[b][SWZ(sr + 32, sc)] = st.b1;
        *(f16x8*)&Bs[b][SWZ(sr + 64, sc)] = st.b2;
        *(f16x8*)&Bs[b][SWZ(sr + 96, sc)] = st.b3;
    };
    auto MM = [&](int b) {
#pragma unroll
        for (int kk = 0; kk < 64; kk += 32) {
            f16x8 afr[2], bfr[4];
#pragma unroll
            for (int i = 0; i < 2; ++i)
                afr[i] = *(const f16x8*)&As[b][SWZ(wm * 32 + i * 16 + li, kk + rk)];
#pragma unroll
            for (int f = 0; f < 4; ++f)
                bfr[f] = *(const f16x8*)&Bs[b][SWZ(wn * 64 + f * 16 + li, kk + rk)];
#pragma unroll
            for (int i = 0; i < 2; ++i)
#pragma unroll
                for (int f = 0; f < 4; ++f)
                    acc[i][f] = __builtin_amdgcn_mfma_f32_16x16x32_f16(
                        afr[i], bfr[f], acc[i][f], 0, 0, 0);
        }
    };

    Stage r = LD(0);
    WRb(0, r);
    r = LD(64);
    int cur = 0;
#pragma unroll 1
    for (int t = 0; t < INTERX / 64; ++t) {
        __syncthreads();
        Stage nxt = LD(t + 2 < INTERX / 64 ? (t + 2) * 64 : 0);
        MM(cur);
        WRb(cur ^ 1, r);
        r = nxt;
        cur ^= 1;
    }

#pragma unroll
    for (int i = 0; i < 2; ++i) {
#pragma unroll
        for (int q = 0; q < 4; ++q) {
            const int m = m0 + wm * 32 + i * 16 + (lane >> 4) * 4 + q;
            if (m >= Me) continue;
            float* yp = yc + (size_t)(rowbase + m) * DIMX + n0 + wn * 64 + li;
#pragma unroll
            for (int f = 0; f < 4; ++f)
                yp[f * 16] = acc[i][f][q];
        }
    }
}

// ---------------------------------------------------------------------------
// Combine: out[t,:] = yc[shared_row(t),:] + sum_k wq[t,k] * yc[row(t,k),:]
// ---------------------------------------------------------------------------
__global__ __launch_bounds__(256) void combine(
    const int* __restrict__ counts,
    const int* __restrict__ slots,
    const float* __restrict__ wq,
    const float* __restrict__ yc,
    float* __restrict__ out)
{
    __shared__ int soff[NEXP];
    if (threadIdx.x < NEXP) {
        int o = 0;
        for (int i = 0; i < (int)threadIdx.x; ++i) o += counts[i];
        soff[threadIdx.x] = o;
    }
    __syncthreads();

    const int t = blockIdx.x;
    const int tid = threadIdx.x;                 // 256 threads x float4 = 1024 cols
    const float4* ycv = (const float4*)yc;
    float4 a = ycv[(size_t)(4096 + t) * 256 + tid];
#pragma unroll
    for (int k = 0; k < 4; ++k) {
        const int s   = slots[t * 4 + k];
        const int e   = s >> 10, pos = s & 1023;
        const float w = wq[t * 4 + k];
        const float4 v = ycv[(size_t)(soff[e] + pos) * 256 + tid];
        a.x = fmaf(w, v.x, a.x); a.y = fmaf(w, v.y, a.y);
        a.z = fmaf(w, v.z, a.z); a.w = fmaf(w, v.w, a.w);
    }
    ((float4*)out)[(size_t)t * 256 + tid] = a;
}

// ---------------------------------------------------------------------------
extern "C" void kernel_launch(void* const* d_in, const int* in_sizes, int n_in,
                              void* d_out, int out_size, void* d_ws, size_t ws_size,
                              hipStream_t stream)
{
    const float* x    = (const float*)d_in[0];
    // d_in[1] = input_ids (unused)
    const float* gw   = (const float*)d_in[2];
    const float* gb   = (const float*)d_in[3];
    const float* w13  = (const float*)d_in[4];
    const float* w2   = (const float*)d_in[5];
    const float* w13s = (const float*)d_in[6];
    const float* w2s  = (const float*)d_in[7];
    float* out = (float*)d_out;

    char* ws = (char*)d_ws;
    int*       counts  = (int*)(ws + WS_COUNTS);
    int*       tok_idx = (int*)(ws + WS_TOKIDX);
    int*       slots   = (int*)(ws + WS_SLOTS);
    float*     wq      = (float*)(ws + WS_WQ);
    _Float16*  h       = (_Float16*)(ws + WS_H);
    float*     yc      = (float*)(ws + WS_YC);
    _Float16*  dh      = (_Float16*)(ws + WS_F16);
    _Float16*  w13h    = dh;
    _Float16*  w2h     = w13h + N_W13;
    _Float16*  w13sh   = w2h + N_W2;
    _Float16*  w2sh    = w13sh + N_W13S;
    _Float16*  xh      = w2sh + N_W2S;

    const bool F16 = (ws_size >= WS_NEED);

    hipMemsetAsync(counts, 0, NEXP * sizeof(int), stream);
    cvt_gate<<<256 + (F16 ? CVT_BLOCKS : 0), 256, 0, stream>>>(
        w13, w2, w13s, w2s, x, dh, gw, gb, counts, tok_idx, slots, wq);

    dim3 g1(16, 8, 17);   // m-tiles, h-col tiles, experts(+shared)
    dim3 g2(16, 8, 17);   // m-tiles, out-col tiles, experts(+shared)
    if (F16) {
        ffn1<true><<<g1, 256, 0, stream>>>(x, xh, w13, w13s, w13h, w13sh,
                                           counts, tok_idx, h);
        ffn2<true><<<g2, 256, 0, stream>>>(w2, w2s, w2h, w2sh, counts, h, yc);
    } else {
        ffn1<false><<<g1, 256, 0, stream>>>(x, xh, w13, w13s, w13h, w13sh,
                                            counts, tok_idx, h);
        ffn2<false><<<g2, 256, 0, stream>>>(w2, w2s, w2h, w2sh, counts, h, yc);
    }
    combine<<<NTOK, 256, 0, stream>>>(counts, slots, wq, yc, out);
}